// Round 9
// baseline (160.324 us; speedup 1.0000x reference)
//
#include <hip/hip_runtime.h>
#include <hip/hip_bf16.h>
#include <math.h>

typedef __attribute__((ext_vector_type(8))) short bf16x8;
typedef __attribute__((ext_vector_type(4))) float f32x4;
typedef __attribute__((ext_vector_type(4))) int   i32x4;

#define NHh 16
#define Sq  2048
#define HIDq 1024
#define HDq 64
#define LOG2E 1.4426950408889634f

#if __has_builtin(__builtin_amdgcn_exp2f)
#define EXP2F(x) __builtin_amdgcn_exp2f(x)
#else
#define EXP2F(x) exp2f(x)
#endif
#if __has_builtin(__builtin_amdgcn_rcpf)
#define RCPF(x) __builtin_amdgcn_rcpf(x)
#else
#define RCPF(x) (1.0f/(x))
#endif

__device__ __forceinline__ unsigned short f2bf(float f){
  union { float f; unsigned u; } v; v.f = f;
  unsigned r = v.u + 0x7fffu + ((v.u >> 16) & 1u);   // RNE
  return (unsigned short)(r >> 16);
}
__device__ __forceinline__ float bf2f(unsigned short s){
  union { unsigned u; float f; } v; v.u = ((unsigned)s) << 16;
  return v.f;
}
__device__ __forceinline__ unsigned pk2bf(float lo, float hi){
  union { __hip_bfloat162 h; unsigned u; } w;
  w.h = __float22bfloat162_rn(make_float2(lo, hi));
  return w.u;
}

// async global->LDS, 16B per lane; LDS dest = wave-uniform base + lane*16 (linear)
__device__ __forceinline__ void gload_lds16(const unsigned short* g, unsigned short* l){
  __builtin_amdgcn_global_load_lds(
      (const __attribute__((address_space(1))) unsigned int*)g,
      (__attribute__((address_space(3))) unsigned int*)l, 16, 0, 0);
}

// ---------------- convert x (f32 -> bf16) + mask -> f32 0/-1e30 tail ----------------
__global__ __launch_bounds__(256) void convert_x(const float* __restrict__ in,
                                                 unsigned short* __restrict__ out, int n8,
                                                 const int* __restrict__ mask,
                                                 float* __restrict__ Mf){
  int bid = blockIdx.x;
  int nmain = gridDim.x - 2;
  if (bid >= nmain){
    int base = (bid - nmain)*2048 + threadIdx.x*8;
    #pragma unroll
    for (int j=0;j<8;j++) Mf[base+j] = mask[base+j] ? 0.f : -1e30f;
    return;
  }
  int i = bid*256 + threadIdx.x;
  if (i >= n8) return;
  const f32x4* p = (const f32x4*)(in + (size_t)i*8);
  f32x4 a = p[0], b = p[1];
  union { unsigned short us[8]; i32x4 v; } o;
  #pragma unroll
  for (int j=0;j<4;j++){ o.us[j] = f2bf(a[j]); o.us[4+j] = f2bf(b[j]); }
  *(i32x4*)(out + (size_t)i*8) = o.v;
}

// ------------- transpose+convert weights: w[K][N] f32 -> wT[N][K] bf16 -------------
__global__ __launch_bounds__(256) void transpose_w(const float* __restrict__ w0, const float* __restrict__ w1,
                                                   const float* __restrict__ w2, const float* __restrict__ w3,
                                                   unsigned short* __restrict__ wT){
  __shared__ float tile[32][33];
  int z = blockIdx.z;
  const float* w = (z==0)?w0:(z==1)?w1:(z==2)?w2:w3;
  unsigned short* dst = wT + (size_t)z*HIDq*HIDq;
  int tx = threadIdx.x, ty = threadIdx.y;
  int n0 = blockIdx.x*32, k0 = blockIdx.y*32;
  #pragma unroll
  for (int i=ty;i<32;i+=8) tile[i][tx] = w[(size_t)(k0+i)*HIDq + n0+tx];
  __syncthreads();
  #pragma unroll
  for (int i=ty;i<32;i+=8) dst[(size_t)(n0+i)*HIDq + k0+tx] = f2bf(tile[tx][i]);
}

// ------------- GEMM main loop: gload_lds, BK=64, granule-XOR swizzled LDS (T2) -------------
__device__ __forceinline__ void gemm_core_gl(const unsigned short* __restrict__ Ag,
                                             const unsigned short* __restrict__ Bg,
                                             unsigned short* As, unsigned short* Bs,
                                             int t, int wv, int lane, int wr, int wc, int lr, int g,
                                             f32x4 acc[4][4]){
  for (int k0=0; k0<HIDq; k0+=64){
    __syncthreads();
    #pragma unroll
    for (int j=0;j<4;j++){
      int flat = (j*4+wv)*64 + lane;      // 0..1023, wave-uniform LDS base + lane*16
      int row = flat>>3, c = flat&7;
      int srcc = (c ^ (row&7))*8;
      gload_lds16(Ag + (size_t)row*HIDq + k0 + srcc, &As[flat*8]);
      gload_lds16(Bg + (size_t)row*HIDq + k0 + srcc, &Bs[flat*8]);
    }
    __syncthreads();
    #pragma unroll
    for (int ks=0; ks<2; ks++){
      bf16x8 af[4], bfv[4];
      #pragma unroll
      for (int m=0;m<4;m++){
        int rr = wr + m*16 + lr;
        af[m]  = *(bf16x8*)&As[rr*64 + (((ks*4+g) ^ (rr&7))*8)];
      }
      #pragma unroll
      for (int n=0;n<4;n++){
        int rr = wc + n*16 + lr;
        bfv[n] = *(bf16x8*)&Bs[rr*64 + (((ks*4+g) ^ (rr&7))*8)];
      }
      #pragma unroll
      for (int n=0;n<4;n++)
        #pragma unroll
        for (int m=0;m<4;m++)
          acc[n][m] = __builtin_amdgcn_mfma_f32_16x16x32_bf16(bfv[n], af[m], acc[n][m], 0,0,0);
    }
  }
}

// ------------- fused QKV projection -------------
__global__ __launch_bounds__(256) void gemm_qkv(const unsigned short* __restrict__ xbf,
    const unsigned short* __restrict__ wT,
    const float* __restrict__ q_b, const float* __restrict__ k_b, const float* __restrict__ v_b,
    unsigned short* __restrict__ Qeff, unsigned short* __restrict__ Keff,
    unsigned short* __restrict__ Vt){
  __shared__ unsigned short As[128*64];
  __shared__ unsigned short Bs[128*64];
  const int t = threadIdx.x;
  const int wv = t>>6, lane = t&63, g = lane>>4, lr = lane&15;
  const int wr = (wv>>1)*64, wc = (wv&1)*64;
  f32x4 acc[4][4] = {};
  const int xb = blockIdx.x, yb = blockIdx.y;
  const float VS = 0.25501335f;   // log2e / sqrt(32)

  if (xb < 16){
    const int row0 = yb*128, col0 = xb*128;
    gemm_core_gl(xbf + (size_t)row0*HIDq, wT + (size_t)col0*HIDq, As, Bs, t, wv, lane, wr, wc, lr, g, acc);
    #pragma unroll
    for (int n=0;n<4;n++){
      #pragma unroll
      for (int m=0;m<4;m++){
        int row = row0 + wr + m*16 + lr;
        int b_ = row>>11, ss = row&2047;
        int colb = col0 + wc + n*16 + g*4;
        int seg = colb>>10, cw = colb&1023;
        int hh = cw>>6, d = cw&63;
        const float* bp = seg ? k_b : q_b;
        f32x4 bb = *(const f32x4*)&bp[cw];
        float sc = seg ? 1.0f : (d < 32 ? VS : -LOG2E);
        unsigned short* E = seg ? Keff : Qeff;
        float v0 = (acc[n][m][0]+bb[0])*sc, v1 = (acc[n][m][1]+bb[1])*sc;
        float v2 = (acc[n][m][2]+bb[2])*sc, v3 = (acc[n][m][3]+bb[3])*sc;
        union { unsigned u[2]; unsigned long long ll; } W;
        W.u[0] = pk2bf(v0,v1); W.u[1] = pk2bf(v2,v3);
        *(unsigned long long*)&E[(((size_t)b_*NHh+hh)*Sq+ss)*HDq + d] = W.ll;
      }
    }
  } else {
    const int row0 = (xb-16)*128, col0 = yb*128;
    gemm_core_gl(wT + (size_t)2*HIDq*HIDq + (size_t)row0*HIDq, xbf + (size_t)col0*HIDq,
                 As, Bs, t, wv, lane, wr, wc, lr, g, acc);
    #pragma unroll
    for (int n=0;n<4;n++){
      #pragma unroll
      for (int m=0;m<4;m++){
        int chan = row0 + wr + m*16 + lr;
        int hh = chan>>6, d = chan&63;
        float bv = v_b[chan];
        int colb = col0 + wc + n*16 + g*4;
        int b_ = colb>>11, ss = colb&2047;
        union { unsigned u[2]; unsigned long long ll; } W;
        W.u[0] = pk2bf(acc[n][m][0]+bv, acc[n][m][1]+bv);
        W.u[1] = pk2bf(acc[n][m][2]+bv, acc[n][m][3]+bv);
        *(unsigned long long*)&Vt[(((size_t)b_*NHh+hh)*HDq + d)*Sq + ss] = W.ll;
      }
    }
  }
}

// ------------- output projection: C f32 = A@Bt^T + bias -------------
__global__ __launch_bounds__(256) void gemm_out(const unsigned short* __restrict__ A,
                                                const unsigned short* __restrict__ Bt,
                                                const float* __restrict__ bias,
                                                float* __restrict__ C){
  __shared__ unsigned short As[128*64];
  __shared__ unsigned short Bs[128*64];
  const int t = threadIdx.x;
  const int wv = t>>6, lane = t&63, g = lane>>4, lr = lane&15;
  const int wr = (wv>>1)*64, wc = (wv&1)*64;
  const int row0 = blockIdx.y*128, col0 = blockIdx.x*128;
  f32x4 acc[4][4] = {};
  gemm_core_gl(A + (size_t)row0*HIDq, Bt + (size_t)col0*HIDq, As, Bs, t, wv, lane, wr, wc, lr, g, acc);
  #pragma unroll
  for (int n=0;n<4;n++){
    #pragma unroll
    for (int m=0;m<4;m++){
      int row = row0 + wr + m*16 + lr;
      int colb = col0 + wc + n*16 + g*4;
      f32x4 bb = *(const f32x4*)&bias[colb];
      f32x4 o = acc[n][m] + bb;
      *(f32x4*)&C[(size_t)row*HIDq + colb] = o;
    }
  }
}

// ------------- flash attention: 4 waves, q-tile 64, KVBLK 64 dbuf, static 2-phase unroll -------------
// LDS = 40 KB exactly -> 4 blocks/CU (160 KB), grid 1024 = one full resident pass.
// no-max softmax (verified R6); explicit Ks0/Ks1 names -> loop-invariant LDS addressing.
__global__ __launch_bounds__(256,4) void attn_kernel(
    const unsigned short* __restrict__ Qe, const unsigned short* __restrict__ Ke,
    const unsigned short* __restrict__ Vt, const float* __restrict__ Tb,
    const float* __restrict__ tbias, const float* __restrict__ Mf,
    unsigned short* __restrict__ Obuf)
{
  __shared__ __align__(16) unsigned char smem[40960];
  unsigned short* Ks0 = (unsigned short*)smem;             // [64 k][64 d] swz, 8 KB
  unsigned short* Ks1 = (unsigned short*)(smem + 8192);
  unsigned short* Vs0 = (unsigned short*)(smem + 16384);   // [64 d][64 k] swz, 8 KB
  unsigned short* Vs1 = (unsigned short*)(smem + 24576);
  unsigned short* Pl  = (unsigned short*)(smem + 32768);   // 4 waves x [16 q][64 k], 8 KB
  float* qls = (float*)smem;                               // prologue overlay, 8.3 KB (pre-staging)
  unsigned short* qtls = Pl;                               // prologue overlay, 5 KB

  const int t = threadIdx.x;
  // XCD-aware decode: all 32 q-blocks of a (b,h) land on one XCD (4 bh per XCD)
  const int dd = blockIdx.x;
  const int slot = dd>>3, xcd = dd&7;
  const int x = slot & 31;
  const int bh = ((slot>>5)<<3) | xcd;
  const int h = bh & 15, b = bh >> 4;
  const int q0 = x*64;
  const int wv = t>>6, lane = t&63, g = lane>>4, lr = lane&15;

  const unsigned short* Qb  = Qe + (((size_t)b*NHh+h)*Sq + q0)*HDq;
  const unsigned short* Kb  = Ke + ((size_t)b*NHh+h)*(size_t)Sq*HDq;
  const unsigned short* Vtb = Vt + ((size_t)b*NHh+h)*(size_t)HDq*Sq;
  const float* Mfb = Mf + (size_t)b*Sq;

  // ---- prologue: qt = q_type(-log2e-scaled) @ T[h] ----
  {
    int row = t>>2, c8 = (t&3)*8;
    bf16x8 v = *(const bf16x8*)(Qb + (size_t)row*HDq + 32 + c8);
    #pragma unroll
    for (int j=0;j<8;j++) qls[row*33 + c8 + j] = bf2f((unsigned short)v[j]);
  }
  __syncthreads();
  {
    int row = t&63, e0 = (t>>6)*8;
    const float* Th = Tb + (size_t)h*1024;
    float a[8] = {};
    #pragma unroll 4
    for (int d=0; d<32; d++){
      float qd = qls[row*33 + d];
      const f32x4* tp = (const f32x4*)(Th + d*32 + e0);
      f32x4 t0 = tp[0], t1 = tp[1];
      a[0]+=qd*t0[0]; a[1]+=qd*t0[1]; a[2]+=qd*t0[2]; a[3]+=qd*t0[3];
      a[4]+=qd*t1[0]; a[5]+=qd*t1[1]; a[6]+=qd*t1[2]; a[7]+=qd*t1[3];
    }
    union { unsigned u[2]; unsigned long long ll; } W0, W1;
    W0.u[0]=pk2bf(a[0],a[1]); W0.u[1]=pk2bf(a[2],a[3]);
    W1.u[0]=pk2bf(a[4],a[5]); W1.u[1]=pk2bf(a[6],a[7]);
    *(unsigned long long*)&qtls[row*40 + e0]     = W0.ll;
    *(unsigned long long*)&qtls[row*40 + e0 + 4] = W1.ll;
  }
  bf16x8 qvf = *(const bf16x8*)(Qb + (size_t)(wv*16+lr)*HDq + g*8);   // val half (prescaled)
  __syncthreads();   // qls reads & qtls writes complete
  bf16x8 qtn = *(const bf16x8*)&qtls[(wv*16+lr)*40 + g*8];            // type half (neg-scaled)

  // ---- stage tile 0 (keys 0..63) into buf0: 512 K-chunks + 512 V-chunks, 2+2 per thread ----
  #pragma unroll
  for (int i=0;i<2;i++){
    int c = t + i*256;
    int kr = c>>3, kc = c&7;
    gload_lds16(Kb + (size_t)kr*HDq + ((kc ^ (kr&7))*8), Ks0 + c*8);
    int vd = c>>3, vc = c&7;
    gload_lds16(Vtb + (size_t)vd*Sq + ((vc ^ (vd&7))*8), Vs0 + c*8);
  }
  __syncthreads();   // qtn read done (Pl reusable) + tile-0 staged (vmcnt drained)

  const float tbn = -tbias[h]*LOG2E;
  const f32x4 tbc = {tbn,tbn,tbn,tbn};
  f32x4 oT[4] = {};
  f32x4 lsum = {0.f,0.f,0.f,0.f};
  unsigned short* Pw = &Pl[wv*1024 + lr*64];
  const int swp = (lr&7)*8;
  bf16x8 onesf;
  #pragma unroll
  for (int j=0;j<8;j++) onesf[j] = (short)0x3F80;

  // one 64-key phase: compute from (Kc,Vc) at key0; optionally stage key0n into (Kn,Vn)
  auto phase = [&](const unsigned short* Kc, const unsigned short* Vc, int key0,
                   bool doStage, int key0n, unsigned short* Kn, unsigned short* Vn){
    f32x4 madd[4];
    #pragma unroll
    for (int ks=0; ks<4; ks++)
      madd[ks] = *(const f32x4*)(Mfb + key0 + ks*16 + g*4);
    if (doStage){
      #pragma unroll
      for (int i=0;i<2;i++){
        int c = t + i*256;
        int kr = c>>3, kc = c&7;
        gload_lds16(Kb + (size_t)(key0n+kr)*HDq + ((kc ^ (kr&7))*8), Kn + c*8);
        int vd = c>>3, vc = c&7;
        gload_lds16(Vtb + (size_t)vd*Sq + key0n + ((vc ^ (vd&7))*8), Vn + c*8);
      }
    }
    // QK^T swapped: lane holds S[q=lr][k = ks*16+4g+r]; mask/bias via MFMA C-operand
    f32x4 sv[4], st[4];
    __builtin_amdgcn_s_setprio(1);
    #pragma unroll
    for (int ks=0; ks<4; ks++){
      const unsigned short* kb = Kc + (ks*16+lr)*64;
      bf16x8 kf0 = *(const bf16x8*)(kb + (((g  ) ^ (lr&7))*8));
      bf16x8 kf1 = *(const bf16x8*)(kb + (((4+g) ^ (lr&7))*8));
      sv[ks] = __builtin_amdgcn_mfma_f32_16x16x32_bf16(kf0, qvf, madd[ks], 0,0,0);
      st[ks] = __builtin_amdgcn_mfma_f32_16x16x32_bf16(kf1, qtn, tbc, 0,0,0);
    }
    __builtin_amdgcn_s_setprio(0);
    // p = exp2(sv) * sigmoid2(st); pack; vector LDS write
    #pragma unroll
    for (int ks=0; ks<4; ks++){
      float p0 = EXP2F(sv[ks][0]) * RCPF(1.f + EXP2F(st[ks][0]));
      float p1 = EXP2F(sv[ks][1]) * RCPF(1.f + EXP2F(st[ks][1]));
      float p2 = EXP2F(sv[ks][2]) * RCPF(1.f + EXP2F(st[ks][2]));
      float p3 = EXP2F(sv[ks][3]) * RCPF(1.f + EXP2F(st[ks][3]));
      union { unsigned u[2]; unsigned long long ll; } W;
      W.u[0] = pk2bf(p0,p1); W.u[1] = pk2bf(p2,p3);
      *(unsigned long long*)(Pw + ((ks*16 + g*4) ^ swp)) = W.ll;
    }
    // PV: oT[d][q] += V^T * P ; lsum via ones-MFMA
    #pragma unroll
    for (int ks2=0; ks2<2; ks2++){
      bf16x8 pf = *(const bf16x8*)(Pw + ((ks2*32 + g*8) ^ swp));
      __builtin_amdgcn_s_setprio(1);
      lsum = __builtin_amdgcn_mfma_f32_16x16x32_bf16(onesf, pf, lsum, 0,0,0);
      #pragma unroll
      for (int db=0; db<4; db++){
        bf16x8 vf = *(const bf16x8*)(Vc + (db*16+lr)*64 + (((ks2*4+g) ^ (lr&7))*8));
        oT[db] = __builtin_amdgcn_mfma_f32_16x16x32_bf16(vf, pf, oT[db], 0,0,0);
      }
      __builtin_amdgcn_s_setprio(0);
    }
  };

  for (int kt=0; kt<Sq; kt+=128){
    phase(Ks0, Vs0, kt,      true,           kt+64,  Ks1, Vs1);
    __syncthreads();
    phase(Ks1, Vs1, kt+64,   kt+128 < Sq,    kt+128, Ks0, Vs0);
    __syncthreads();
  }

  // ---- epilogue: lane q = lr; oT[db][r] = O[d=db*16+4g+r][q] ----
  float linv = (lsum[0] > 0.f) ? RCPF(lsum[0]) : 0.f;
  int srow = q0 + wv*16 + lr;
  unsigned short* Ob = Obuf + ((size_t)b*Sq + srow)*HIDq + h*HDq;
  #pragma unroll
  for (int db=0; db<4; db++){
    union { unsigned u[2]; unsigned long long ll; } W;
    W.u[0] = pk2bf(oT[db][0]*linv, oT[db][1]*linv);
    W.u[1] = pk2bf(oT[db][2]*linv, oT[db][3]*linv);
    *(unsigned long long*)(Ob + db*16 + g*4) = W.ll;
  }
}

extern "C" void kernel_launch(void* const* d_in, const int* in_sizes, int n_in,
                              void* d_out, int out_size, void* d_ws, size_t ws_size,
                              hipStream_t stream) {
  const float* x     = (const float*)d_in[0];
  const float* q_w   = (const float*)d_in[1];
  const float* q_b   = (const float*)d_in[2];
  const float* k_w   = (const float*)d_in[3];
  const float* k_b   = (const float*)d_in[4];
  const float* v_w   = (const float*)d_in[5];
  const float* v_b   = (const float*)d_in[6];
  const float* out_w = (const float*)d_in[7];
  const float* out_b = (const float*)d_in[8];
  const float* Tb    = (const float*)d_in[9];
  const float* tbias = (const float*)d_in[10];
  const int*   mask  = (const int*)d_in[11];

  const size_t MROWS = 4096;             // B*S
  unsigned short* xbf  = (unsigned short*)d_ws;           // 4M shorts
  unsigned short* wT   = xbf  + MROWS*HIDq;               // 4 x 1M
  unsigned short* Qeff = wT   + (size_t)4*HIDq*HIDq;      // (B,NH,S,HD), prescaled
  unsigned short* Keff = Qeff + MROWS*HIDq;
  unsigned short* Vt   = Keff + MROWS*HIDq;               // (B,NH,HD,S) transposed
  unsigned short* Obuf = Vt   + MROWS*HIDq;               // (B,S,HID) bf16
  float*          Mf   = (float*)(Obuf + MROWS*HIDq);     // (B,S) f32 mask adds

  int n8 = (int)(MROWS*HIDq/8);
  convert_x<<<dim3(n8/256 + 2), dim3(256), 0, stream>>>(x, xbf, n8, mask, Mf);
  transpose_w<<<dim3(32,32,4), dim3(32,8), 0, stream>>>(q_w, k_w, v_w, out_w, wT);

  gemm_qkv<<<dim3(24,32), dim3(256), 0, stream>>>(xbf, wT, q_b, k_b, v_b, Qeff, Keff, Vt);

  attn_kernel<<<dim3(1024), dim3(256), 0, stream>>>(Qeff, Keff, Vt, Tb, tbias, Mf, Obuf);

  gemm_out<<<dim3(8,32), dim3(256), 0, stream>>>(Obuf, wT + (size_t)3*HIDq*HIDq, out_b, (float*)d_out);
}

// Round 11
// 158.922 us; speedup vs baseline: 1.0088x; 1.0088x over previous
//
#include <hip/hip_runtime.h>
#include <hip/hip_bf16.h>
#include <math.h>

typedef __attribute__((ext_vector_type(8))) short bf16x8;
typedef __attribute__((ext_vector_type(4))) short bf16x4;
typedef __attribute__((ext_vector_type(4))) float f32x4;
typedef __attribute__((ext_vector_type(4))) int   i32x4;

#define NHh 16
#define Sq  2048
#define HIDq 1024
#define HDq 64
#define LOG2E 1.4426950408889634f

#if __has_builtin(__builtin_amdgcn_exp2f)
#define EXP2F(x) __builtin_amdgcn_exp2f(x)
#else
#define EXP2F(x) exp2f(x)
#endif
#if __has_builtin(__builtin_amdgcn_rcpf)
#define RCPF(x) __builtin_amdgcn_rcpf(x)
#else
#define RCPF(x) (1.0f/(x))
#endif

// 16x16x16 bf16 MFMA: D[q][d] += A[q][k]*B[k][d]; A,B = bf16x4 (2 VGPRs each)
#if __has_builtin(__builtin_amdgcn_mfma_f32_16x16x16bf16_1k)
__device__ __forceinline__ f32x4 MFMA16(bf16x4 a, bf16x4 b, f32x4 c){
  return __builtin_amdgcn_mfma_f32_16x16x16bf16_1k(a, b, c, 0, 0, 0);
}
#else
__device__ __forceinline__ f32x4 MFMA16(bf16x4 a, bf16x4 b, f32x4 c){
  asm volatile("v_mfma_f32_16x16x16_bf16 %0, %1, %2, %0\n\ts_nop 7\n\ts_nop 7"
               : "+v"(c) : "v"(a), "v"(b));
  return c;
}
#endif

__device__ __forceinline__ unsigned short f2bf(float f){
  union { float f; unsigned u; } v; v.f = f;
  unsigned r = v.u + 0x7fffu + ((v.u >> 16) & 1u);   // RNE
  return (unsigned short)(r >> 16);
}
__device__ __forceinline__ float bf2f(unsigned short s){
  union { unsigned u; float f; } v; v.u = ((unsigned)s) << 16;
  return v.f;
}
__device__ __forceinline__ unsigned pk2bf(float lo, float hi){
  union { __hip_bfloat162 h; unsigned u; } w;
  w.h = __float22bfloat162_rn(make_float2(lo, hi));
  return w.u;
}

// async global->LDS, 16B per lane; LDS dest = wave-uniform base + lane*16 (linear)
__device__ __forceinline__ void gload_lds16(const unsigned short* g, unsigned short* l){
  __builtin_amdgcn_global_load_lds(
      (const __attribute__((address_space(1))) unsigned int*)g,
      (__attribute__((address_space(3))) unsigned int*)l, 16, 0, 0);
}

// ---------------- convert x (f32 -> bf16) + mask -> bf16 0/1 tail ----------------
__global__ __launch_bounds__(256) void convert_x(const float* __restrict__ in,
                                                 unsigned short* __restrict__ out, int n8,
                                                 const int* __restrict__ mask,
                                                 unsigned short* __restrict__ Mbf){
  int bid = blockIdx.x;
  int nmain = gridDim.x - 2;
  if (bid >= nmain){
    int base = (bid - nmain)*2048 + threadIdx.x*8;
    #pragma unroll
    for (int j=0;j<8;j++) Mbf[base+j] = mask[base+j] ? (unsigned short)0x3F80 : (unsigned short)0;
    return;
  }
  int i = bid*256 + threadIdx.x;
  if (i >= n8) return;
  const f32x4* p = (const f32x4*)(in + (size_t)i*8);
  f32x4 a = p[0], b = p[1];
  union { unsigned short us[8]; i32x4 v; } o;
  #pragma unroll
  for (int j=0;j<4;j++){ o.us[j] = f2bf(a[j]); o.us[4+j] = f2bf(b[j]); }
  *(i32x4*)(out + (size_t)i*8) = o.v;
}

// ------------- transpose+convert weights: w[K][N] f32 -> wT[N][K] bf16 -------------
__global__ __launch_bounds__(256) void transpose_w(const float* __restrict__ w0, const float* __restrict__ w1,
                                                   const float* __restrict__ w2, const float* __restrict__ w3,
                                                   unsigned short* __restrict__ wT){
  __shared__ float tile[32][33];
  int z = blockIdx.z;
  const float* w = (z==0)?w0:(z==1)?w1:(z==2)?w2:w3;
  unsigned short* dst = wT + (size_t)z*HIDq*HIDq;
  int tx = threadIdx.x, ty = threadIdx.y;
  int n0 = blockIdx.x*32, k0 = blockIdx.y*32;
  #pragma unroll
  for (int i=ty;i<32;i+=8) tile[i][tx] = w[(size_t)(k0+i)*HIDq + n0+tx];
  __syncthreads();
  #pragma unroll
  for (int i=ty;i<32;i+=8) dst[(size_t)(n0+i)*HIDq + k0+tx] = f2bf(tile[tx][i]);
}

// ------------- GEMM main loop: gload_lds, BK=64, granule-XOR swizzled LDS (T2) -------------
__device__ __forceinline__ void gemm_core_gl(const unsigned short* __restrict__ Ag,
                                             const unsigned short* __restrict__ Bg,
                                             unsigned short* As, unsigned short* Bs,
                                             int t, int wv, int lane, int wr, int wc, int lr, int g,
                                             f32x4 acc[4][4]){
  for (int k0=0; k0<HIDq; k0+=64){
    __syncthreads();
    #pragma unroll
    for (int j=0;j<4;j++){
      int flat = (j*4+wv)*64 + lane;      // 0..1023, wave-uniform LDS base + lane*16
      int row = flat>>3, c = flat&7;
      int srcc = (c ^ (row&7))*8;
      gload_lds16(Ag + (size_t)row*HIDq + k0 + srcc, &As[flat*8]);
      gload_lds16(Bg + (size_t)row*HIDq + k0 + srcc, &Bs[flat*8]);
    }
    __syncthreads();
    #pragma unroll
    for (int ks=0; ks<2; ks++){
      bf16x8 af[4], bfv[4];
      #pragma unroll
      for (int m=0;m<4;m++){
        int rr = wr + m*16 + lr;
        af[m]  = *(bf16x8*)&As[rr*64 + (((ks*4+g) ^ (rr&7))*8)];
      }
      #pragma unroll
      for (int n=0;n<4;n++){
        int rr = wc + n*16 + lr;
        bfv[n] = *(bf16x8*)&Bs[rr*64 + (((ks*4+g) ^ (rr&7))*8)];
      }
      #pragma unroll
      for (int n=0;n<4;n++)
        #pragma unroll
        for (int m=0;m<4;m++)
          acc[n][m] = __builtin_amdgcn_mfma_f32_16x16x32_bf16(bfv[n], af[m], acc[n][m], 0,0,0);
    }
  }
}

// ------------- fused QKV projection (V rows pre-masked) -------------
__global__ __launch_bounds__(256) void gemm_qkv(const unsigned short* __restrict__ xbf,
    const unsigned short* __restrict__ wT,
    const float* __restrict__ q_b, const float* __restrict__ k_b, const float* __restrict__ v_b,
    const int* __restrict__ mask,
    unsigned short* __restrict__ Qeff, unsigned short* __restrict__ Keff,
    unsigned short* __restrict__ Vt){
  __shared__ unsigned short As[128*64];
  __shared__ unsigned short Bs[128*64];
  const int t = threadIdx.x;
  const int wv = t>>6, lane = t&63, g = lane>>4, lr = lane&15;
  const int wr = (wv>>1)*64, wc = (wv&1)*64;
  f32x4 acc[4][4] = {};
  const int xb = blockIdx.x, yb = blockIdx.y;
  const float VS = 0.25501335f;   // log2e / sqrt(32)

  if (xb < 16){
    const int row0 = yb*128, col0 = xb*128;
    gemm_core_gl(xbf + (size_t)row0*HIDq, wT + (size_t)col0*HIDq, As, Bs, t, wv, lane, wr, wc, lr, g, acc);
    #pragma unroll
    for (int n=0;n<4;n++){
      #pragma unroll
      for (int m=0;m<4;m++){
        int row = row0 + wr + m*16 + lr;
        int b_ = row>>11, ss = row&2047;
        int colb = col0 + wc + n*16 + g*4;
        int seg = colb>>10, cw = colb&1023;
        int hh = cw>>6, d = cw&63;
        const float* bp = seg ? k_b : q_b;
        f32x4 bb = *(const f32x4*)&bp[cw];
        float sc = seg ? 1.0f : (d < 32 ? VS : -LOG2E);
        unsigned short* E = seg ? Keff : Qeff;
        float v0 = (acc[n][m][0]+bb[0])*sc, v1 = (acc[n][m][1]+bb[1])*sc;
        float v2 = (acc[n][m][2]+bb[2])*sc, v3 = (acc[n][m][3]+bb[3])*sc;
        union { unsigned u[2]; unsigned long long ll; } W;
        W.u[0] = pk2bf(v0,v1); W.u[1] = pk2bf(v2,v3);
        *(unsigned long long*)&E[(((size_t)b_*NHh+hh)*Sq+ss)*HDq + d] = W.ll;
      }
    }
  } else {
    const int row0 = (xb-16)*128, col0 = yb*128;
    gemm_core_gl(wT + (size_t)2*HIDq*HIDq + (size_t)row0*HIDq, xbf + (size_t)col0*HIDq,
                 As, Bs, t, wv, lane, wr, wc, lr, g, acc);
    #pragma unroll
    for (int n=0;n<4;n++){
      #pragma unroll
      for (int m=0;m<4;m++){
        int chan = row0 + wr + m*16 + lr;
        int hh = chan>>6, d = chan&63;
        float bv = v_b[chan];
        int colb = col0 + wc + n*16 + g*4;
        int b_ = colb>>11, ss = colb&2047;
        i32x4 mk = *(const i32x4*)&mask[(size_t)b_*Sq + ss];   // zero masked V rows
        float m0 = mk[0]?1.f:0.f, m1 = mk[1]?1.f:0.f, m2 = mk[2]?1.f:0.f, m3 = mk[3]?1.f:0.f;
        union { unsigned u[2]; unsigned long long ll; } W;
        W.u[0] = pk2bf((acc[n][m][0]+bv)*m0, (acc[n][m][1]+bv)*m1);
        W.u[1] = pk2bf((acc[n][m][2]+bv)*m2, (acc[n][m][3]+bv)*m3);
        *(unsigned long long*)&Vt[(((size_t)b_*NHh+hh)*HDq + d)*Sq + ss] = W.ll;
      }
    }
  }
}

// ------------- output projection: C f32 = A@Bt^T + bias -------------
__global__ __launch_bounds__(256) void gemm_out(const unsigned short* __restrict__ A,
                                                const unsigned short* __restrict__ Bt,
                                                const float* __restrict__ bias,
                                                float* __restrict__ C){
  __shared__ unsigned short As[128*64];
  __shared__ unsigned short Bs[128*64];
  const int t = threadIdx.x;
  const int wv = t>>6, lane = t&63, g = lane>>4, lr = lane&15;
  const int wr = (wv>>1)*64, wc = (wv&1)*64;
  const int row0 = blockIdx.y*128, col0 = blockIdx.x*128;
  f32x4 acc[4][4] = {};
  gemm_core_gl(A + (size_t)row0*HIDq, Bt + (size_t)col0*HIDq, As, Bs, t, wv, lane, wr, wc, lr, g, acc);
  #pragma unroll
  for (int n=0;n<4;n++){
    #pragma unroll
    for (int m=0;m<4;m++){
      int row = row0 + wr + m*16 + lr;
      int colb = col0 + wc + n*16 + g*4;
      f32x4 bb = *(const f32x4*)&bias[colb];
      f32x4 o = acc[n][m] + bb;
      *(f32x4*)&C[(size_t)row*HIDq + colb] = o;
    }
  }
}

// ------------- flash attention: 4 waves, q-tile 64, KVBLK 64 dbuf, P-in-register PV -------------
// PV uses mfma_16x16x16: swapped-QK P output IS a valid A-fragment (row=q=lr, k=4g+j)
// -> no cross-lane exchange, no P LDS buffer. LDS = 32 KB. Mask: V rows pre-zeroed +
// lsum = mfma(P, mask_frag). Output orientation O[q][d].
__global__ __launch_bounds__(256,4) void attn_kernel(
    const unsigned short* __restrict__ Qe, const unsigned short* __restrict__ Ke,
    const unsigned short* __restrict__ Vt, const float* __restrict__ Tb,
    const float* __restrict__ tbias, const unsigned short* __restrict__ Mbf,
    unsigned short* __restrict__ Obuf)
{
  __shared__ __align__(16) unsigned char smem[32768];
  unsigned short* Ks0 = (unsigned short*)smem;             // [64 k][64 d] swz, 8 KB
  unsigned short* Ks1 = (unsigned short*)(smem + 8192);
  unsigned short* Vs0 = (unsigned short*)(smem + 16384);   // [64 d][64 k] swz, 8 KB
  unsigned short* Vs1 = (unsigned short*)(smem + 24576);
  float* qls = (float*)smem;                               // prologue overlay (8.3 KB in Ks0+Ks1)
  unsigned short* qtls = Vs0;                              // prologue overlay (5 KB in Vs0)

  const int t = threadIdx.x;
  // XCD-aware decode: all 32 q-blocks of a (b,h) land on one XCD (4 bh per XCD)
  const int dd = blockIdx.x;
  const int slot = dd>>3, xcd = dd&7;
  const int x = slot & 31;
  const int bh = ((slot>>5)<<3) | xcd;
  const int h = bh & 15, b = bh >> 4;
  const int q0 = x*64;
  const int wv = t>>6, lane = t&63, g = lane>>4, lr = lane&15;

  const unsigned short* Qb  = Qe + (((size_t)b*NHh+h)*Sq + q0)*HDq;
  const unsigned short* Kb  = Ke + ((size_t)b*NHh+h)*(size_t)Sq*HDq;
  const unsigned short* Vtb = Vt + ((size_t)b*NHh+h)*(size_t)HDq*Sq;
  const unsigned short* Mbfb = Mbf + (size_t)b*Sq;

  // ---- prologue: qt = q_type(-log2e-scaled) @ T[h] ----
  {
    int row = t>>2, c8 = (t&3)*8;
    bf16x8 v = *(const bf16x8*)(Qb + (size_t)row*HDq + 32 + c8);
    #pragma unroll
    for (int j=0;j<8;j++) qls[row*33 + c8 + j] = bf2f((unsigned short)v[j]);
  }
  __syncthreads();
  {
    int row = t&63, e0 = (t>>6)*8;
    const float* Th = Tb + (size_t)h*1024;
    float a[8] = {};
    #pragma unroll 4
    for (int d=0; d<32; d++){
      float qd = qls[row*33 + d];
      const f32x4* tp = (const f32x4*)(Th + d*32 + e0);
      f32x4 t0 = tp[0], t1 = tp[1];
      a[0]+=qd*t0[0]; a[1]+=qd*t0[1]; a[2]+=qd*t0[2]; a[3]+=qd*t0[3];
      a[4]+=qd*t1[0]; a[5]+=qd*t1[1]; a[6]+=qd*t1[2]; a[7]+=qd*t1[3];
    }
    union { unsigned u[2]; unsigned long long ll; } W0, W1;
    W0.u[0]=pk2bf(a[0],a[1]); W0.u[1]=pk2bf(a[2],a[3]);
    W1.u[0]=pk2bf(a[4],a[5]); W1.u[1]=pk2bf(a[6],a[7]);
    *(unsigned long long*)&qtls[row*40 + e0]     = W0.ll;
    *(unsigned long long*)&qtls[row*40 + e0 + 4] = W1.ll;
  }
  bf16x8 qvf = *(const bf16x8*)(Qb + (size_t)(wv*16+lr)*HDq + g*8);   // val half (prescaled)
  __syncthreads();   // qtls writes visible
  bf16x8 qtn = *(const bf16x8*)&qtls[(wv*16+lr)*40 + g*8];            // type half (neg-scaled)
  __syncthreads();   // all qtn reads done before staging overwrites Vs0

  // ---- stage tile 0 (keys 0..63) into buf0 ----
  #pragma unroll
  for (int i=0;i<2;i++){
    int c = t + i*256;
    int kr = c>>3, kc = c&7;
    gload_lds16(Kb + (size_t)kr*HDq + ((kc ^ (kr&7))*8), Ks0 + c*8);
    int vd = c>>3, vc = c&7;
    gload_lds16(Vtb + (size_t)vd*Sq + ((vc ^ (vd&7))*8), Vs0 + c*8);
  }
  __syncthreads();   // tile-0 staged (vmcnt drained by barrier)

  const float tbn = -tbias[h]*LOG2E;
  const f32x4 tbc = {tbn,tbn,tbn,tbn};
  const f32x4 zf = {0.f,0.f,0.f,0.f};
  f32x4 oT[4] = {};         // oT[db][r] = O[q=4g+r][d=db*16+lr]
  f32x4 lsum = {0.f,0.f,0.f,0.f};   // lsum[r] for q=4g+r

  // one 64-key phase
  auto phase = [&](const unsigned short* Kc, const unsigned short* Vc, int key0,
                   bool doStage, int key0n, unsigned short* Kn, unsigned short* Vn){
    if (doStage){
      #pragma unroll
      for (int i=0;i<2;i++){
        int c = t + i*256;
        int kr = c>>3, kc = c&7;
        gload_lds16(Kb + (size_t)(key0n+kr)*HDq + ((kc ^ (kr&7))*8), Kn + c*8);
        int vd = c>>3, vc = c&7;
        gload_lds16(Vtb + (size_t)vd*Sq + key0n + ((vc ^ (vd&7))*8), Vn + c*8);
      }
    }
    // QK^T swapped: lane holds S[k = 16ks+4g+r][q = lr] = P[q=lr][k]
    f32x4 sv[4], st[4];
    __builtin_amdgcn_s_setprio(1);
    #pragma unroll
    for (int ks=0; ks<4; ks++){
      const unsigned short* kb = Kc + (ks*16+lr)*64;
      bf16x8 kf0 = *(const bf16x8*)(kb + (((g  ) ^ (lr&7))*8));
      bf16x8 kf1 = *(const bf16x8*)(kb + (((4+g) ^ (lr&7))*8));
      sv[ks] = __builtin_amdgcn_mfma_f32_16x16x32_bf16(kf0, qvf, zf, 0,0,0);
      st[ks] = __builtin_amdgcn_mfma_f32_16x16x32_bf16(kf1, qtn, tbc, 0,0,0);
    }
    __builtin_amdgcn_s_setprio(0);
    // p = exp2(sv) * sigmoid2(st); pack into x16 A-fragments (q=lr, k_local=4g+j)
    bf16x4 pa[4];
    #pragma unroll
    for (int ks=0; ks<4; ks++){
      float p0 = EXP2F(sv[ks][0]) * RCPF(1.f + EXP2F(st[ks][0]));
      float p1 = EXP2F(sv[ks][1]) * RCPF(1.f + EXP2F(st[ks][1]));
      float p2 = EXP2F(sv[ks][2]) * RCPF(1.f + EXP2F(st[ks][2]));
      float p3 = EXP2F(sv[ks][3]) * RCPF(1.f + EXP2F(st[ks][3]));
      union { unsigned u[2]; bf16x4 v; } P_;
      P_.u[0] = pk2bf(p0,p1); P_.u[1] = pk2bf(p2,p3);
      pa[ks] = P_.v;
    }
    // PV: O[q][d] += P[q][k] V[k][d] via 16x16x16; lsum via mask B-fragment
    #pragma unroll
    for (int ks=0; ks<4; ks++){
      bf16x4 mfr = *(const bf16x4*)(Mbfb + key0 + ks*16 + g*4);   // B[k][*] = mask[k]
      __builtin_amdgcn_s_setprio(1);
      lsum = MFMA16(pa[ks], mfr, lsum);
      #pragma unroll
      for (int db=0; db<4; db++){
        // B-fragment: V[k = 16ks+4g+j][d = db*16+lr] from Vs[d][k] (granule-swizzled)
        bf16x4 vf = *(const bf16x4*)(Vc + (db*16+lr)*64 + (((2*ks + (g>>1)) ^ (lr&7))*8 + 4*(g&1)));
        oT[db] = MFMA16(pa[ks], vf, oT[db]);
      }
      __builtin_amdgcn_s_setprio(0);
    }
  };

  for (int kt=0; kt<Sq; kt+=128){
    phase(Ks0, Vs0, kt,      true,           kt+64,  Ks1, Vs1);
    __syncthreads();
    phase(Ks1, Vs1, kt+64,   kt+128 < Sq,    kt+128, Ks0, Vs0);
    __syncthreads();
  }

  // ---- epilogue: lane (g,lr) holds O[q = wv*16+4g+r][d = db*16+lr] ----
  float linv[4];
  #pragma unroll
  for (int r=0;r<4;r++) linv[r] = (lsum[r] > 0.f) ? RCPF(lsum[r]) : 0.f;
  unsigned short* Ob = Obuf + ((size_t)b*Sq + (q0 + wv*16 + g*4))*HIDq + h*HDq + lr;
  #pragma unroll
  for (int db=0; db<4; db++){
    #pragma unroll
    for (int r=0;r<4;r++)
      Ob[(size_t)r*HIDq + db*16] = f2bf(oT[db][r]*linv[r]);
  }
}

extern "C" void kernel_launch(void* const* d_in, const int* in_sizes, int n_in,
                              void* d_out, int out_size, void* d_ws, size_t ws_size,
                              hipStream_t stream) {
  const float* x     = (const float*)d_in[0];
  const float* q_w   = (const float*)d_in[1];
  const float* q_b   = (const float*)d_in[2];
  const float* k_w   = (const float*)d_in[3];
  const float* k_b   = (const float*)d_in[4];
  const float* v_w   = (const float*)d_in[5];
  const float* v_b   = (const float*)d_in[6];
  const float* out_w = (const float*)d_in[7];
  const float* out_b = (const float*)d_in[8];
  const float* Tb    = (const float*)d_in[9];
  const float* tbias = (const float*)d_in[10];
  const int*   mask  = (const int*)d_in[11];

  const size_t MROWS = 4096;             // B*S
  unsigned short* xbf  = (unsigned short*)d_ws;           // 4M shorts
  unsigned short* wT   = xbf  + MROWS*HIDq;               // 4 x 1M
  unsigned short* Qeff = wT   + (size_t)4*HIDq*HIDq;      // (B,NH,S,HD), prescaled
  unsigned short* Keff = Qeff + MROWS*HIDq;
  unsigned short* Vt   = Keff + MROWS*HIDq;               // (B,NH,HD,S) transposed, masked rows zeroed
  unsigned short* Obuf = Vt   + MROWS*HIDq;               // (B,S,HID) bf16
  unsigned short* Mbf  = Obuf + MROWS*HIDq;               // (B,S) bf16 0/1 mask

  int n8 = (int)(MROWS*HIDq/8);
  convert_x<<<dim3(n8/256 + 2), dim3(256), 0, stream>>>(x, xbf, n8, mask, Mbf);
  transpose_w<<<dim3(32,32,4), dim3(32,8), 0, stream>>>(q_w, k_w, v_w, out_w, wT);

  gemm_qkv<<<dim3(24,32), dim3(256), 0, stream>>>(xbf, wT, q_b, k_b, v_b, mask, Qeff, Keff, Vt);

  attn_kernel<<<dim3(1024), dim3(256), 0, stream>>>(Qeff, Keff, Vt, Tb, tbias, Mbf, Obuf);

  gemm_out<<<dim3(8,32), dim3(256), 0, stream>>>(Obuf, wT + (size_t)3*HIDq*HIDq, out_b, (float*)d_out);
}

// Round 12
// 152.863 us; speedup vs baseline: 1.0488x; 1.0396x over previous
//
#include <hip/hip_runtime.h>
#include <hip/hip_bf16.h>
#include <math.h>

typedef __attribute__((ext_vector_type(8))) short bf16x8;
typedef __attribute__((ext_vector_type(4))) short bf16x4;
typedef __attribute__((ext_vector_type(4))) float f32x4;
typedef __attribute__((ext_vector_type(4))) int   i32x4;

#define NHh 16
#define Sq  2048
#define HIDq 1024
#define HDq 64
#define LOG2E 1.4426950408889634f

#if __has_builtin(__builtin_amdgcn_exp2f)
#define EXP2F(x) __builtin_amdgcn_exp2f(x)
#else
#define EXP2F(x) exp2f(x)
#endif
#if __has_builtin(__builtin_amdgcn_rcpf)
#define RCPF(x) __builtin_amdgcn_rcpf(x)
#else
#define RCPF(x) (1.0f/(x))
#endif

// 16x16x16 bf16 MFMA: D[q][d] += A[q][k]*B[k][d]
#if __has_builtin(__builtin_amdgcn_mfma_f32_16x16x16bf16_1k)
__device__ __forceinline__ f32x4 MFMA16(bf16x4 a, bf16x4 b, f32x4 c){
  return __builtin_amdgcn_mfma_f32_16x16x16bf16_1k(a, b, c, 0, 0, 0);
}
#else
__device__ __forceinline__ f32x4 MFMA16(bf16x4 a, bf16x4 b, f32x4 c){
  asm volatile("v_mfma_f32_16x16x16_bf16 %0, %1, %2, %0\n\ts_nop 7\n\ts_nop 7"
               : "+v"(c) : "v"(a), "v"(b));
  return c;
}
#endif

__device__ __forceinline__ unsigned short f2bf(float f){
  union { float f; unsigned u; } v; v.f = f;
  unsigned r = v.u + 0x7fffu + ((v.u >> 16) & 1u);   // RNE
  return (unsigned short)(r >> 16);
}
__device__ __forceinline__ float bf2f(unsigned short s){
  union { unsigned u; float f; } v; v.u = ((unsigned)s) << 16;
  return v.f;
}
__device__ __forceinline__ unsigned pk2bf(float lo, float hi){
  union { __hip_bfloat162 h; unsigned u; } w;
  w.h = __float22bfloat162_rn(make_float2(lo, hi));
  return w.u;
}

// async global->LDS, 16B per lane; LDS dest = wave-uniform base + lane*16 (linear)
__device__ __forceinline__ void gload_lds16(const unsigned short* g, unsigned short* l){
  __builtin_amdgcn_global_load_lds(
      (const __attribute__((address_space(1))) unsigned int*)g,
      (__attribute__((address_space(3))) unsigned int*)l, 16, 0, 0);
}

// ---------------- convert x (f32 -> bf16) + mask -> bf16 0/1 tail ----------------
__global__ __launch_bounds__(256) void convert_x(const float* __restrict__ in,
                                                 unsigned short* __restrict__ out, int n8,
                                                 const int* __restrict__ mask,
                                                 unsigned short* __restrict__ Mbf){
  int bid = blockIdx.x;
  int nmain = gridDim.x - 2;
  if (bid >= nmain){
    int base = (bid - nmain)*2048 + threadIdx.x*8;
    #pragma unroll
    for (int j=0;j<8;j++) Mbf[base+j] = mask[base+j] ? (unsigned short)0x3F80 : (unsigned short)0;
    return;
  }
  int i = bid*256 + threadIdx.x;
  if (i >= n8) return;
  const f32x4* p = (const f32x4*)(in + (size_t)i*8);
  f32x4 a = p[0], b = p[1];
  union { unsigned short us[8]; i32x4 v; } o;
  #pragma unroll
  for (int j=0;j<4;j++){ o.us[j] = f2bf(a[j]); o.us[4+j] = f2bf(b[j]); }
  *(i32x4*)(out + (size_t)i*8) = o.v;
}

// ------------- transpose+convert weights: w[K][N] f32 -> wT[N][K] bf16 -------------
__global__ __launch_bounds__(256) void transpose_w(const float* __restrict__ w0, const float* __restrict__ w1,
                                                   const float* __restrict__ w2, const float* __restrict__ w3,
                                                   unsigned short* __restrict__ wT){
  __shared__ float tile[32][33];
  int z = blockIdx.z;
  const float* w = (z==0)?w0:(z==1)?w1:(z==2)?w2:w3;
  unsigned short* dst = wT + (size_t)z*HIDq*HIDq;
  int tx = threadIdx.x, ty = threadIdx.y;
  int n0 = blockIdx.x*32, k0 = blockIdx.y*32;
  #pragma unroll
  for (int i=ty;i<32;i+=8) tile[i][tx] = w[(size_t)(k0+i)*HIDq + n0+tx];
  __syncthreads();
  #pragma unroll
  for (int i=ty;i<32;i+=8) dst[(size_t)(n0+i)*HIDq + k0+tx] = f2bf(tile[tx][i]);
}

// ------------- GEMM main loop: gload_lds, BK=64, granule-XOR swizzled LDS (T2) -------------
__device__ __forceinline__ void gemm_core_gl(const unsigned short* __restrict__ Ag,
                                             const unsigned short* __restrict__ Bg,
                                             unsigned short* As, unsigned short* Bs,
                                             int t, int wv, int lane, int wr, int wc, int lr, int g,
                                             f32x4 acc[4][4]){
  for (int k0=0; k0<HIDq; k0+=64){
    __syncthreads();
    #pragma unroll
    for (int j=0;j<4;j++){
      int flat = (j*4+wv)*64 + lane;
      int row = flat>>3, c = flat&7;
      int srcc = (c ^ (row&7))*8;
      gload_lds16(Ag + (size_t)row*HIDq + k0 + srcc, &As[flat*8]);
      gload_lds16(Bg + (size_t)row*HIDq + k0 + srcc, &Bs[flat*8]);
    }
    __syncthreads();
    #pragma unroll
    for (int ks=0; ks<2; ks++){
      bf16x8 af[4], bfv[4];
      #pragma unroll
      for (int m=0;m<4;m++){
        int rr = wr + m*16 + lr;
        af[m]  = *(bf16x8*)&As[rr*64 + (((ks*4+g) ^ (rr&7))*8)];
      }
      #pragma unroll
      for (int n=0;n<4;n++){
        int rr = wc + n*16 + lr;
        bfv[n] = *(bf16x8*)&Bs[rr*64 + (((ks*4+g) ^ (rr&7))*8)];
      }
      #pragma unroll
      for (int n=0;n<4;n++)
        #pragma unroll
        for (int m=0;m<4;m++)
          acc[n][m] = __builtin_amdgcn_mfma_f32_16x16x32_bf16(bfv[n], af[m], acc[n][m], 0,0,0);
    }
  }
}

// ------------- fused QKV projection (V rows pre-masked) -------------
__global__ __launch_bounds__(256) void gemm_qkv(const unsigned short* __restrict__ xbf,
    const unsigned short* __restrict__ wT,
    const float* __restrict__ q_b, const float* __restrict__ k_b, const float* __restrict__ v_b,
    const int* __restrict__ mask,
    unsigned short* __restrict__ Qeff, unsigned short* __restrict__ Keff,
    unsigned short* __restrict__ Vt){
  __shared__ unsigned short As[128*64];
  __shared__ unsigned short Bs[128*64];
  const int t = threadIdx.x;
  const int wv = t>>6, lane = t&63, g = lane>>4, lr = lane&15;
  const int wr = (wv>>1)*64, wc = (wv&1)*64;
  f32x4 acc[4][4] = {};
  const int xb = blockIdx.x, yb = blockIdx.y;
  const float VS = 0.25501335f;   // log2e / sqrt(32)

  if (xb < 16){
    const int row0 = yb*128, col0 = xb*128;
    gemm_core_gl(xbf + (size_t)row0*HIDq, wT + (size_t)col0*HIDq, As, Bs, t, wv, lane, wr, wc, lr, g, acc);
    #pragma unroll
    for (int n=0;n<4;n++){
      #pragma unroll
      for (int m=0;m<4;m++){
        int row = row0 + wr + m*16 + lr;
        int b_ = row>>11, ss = row&2047;
        int colb = col0 + wc + n*16 + g*4;
        int seg = colb>>10, cw = colb&1023;
        int hh = cw>>6, d = cw&63;
        const float* bp = seg ? k_b : q_b;
        f32x4 bb = *(const f32x4*)&bp[cw];
        float sc = seg ? 1.0f : (d < 32 ? VS : -LOG2E);
        unsigned short* E = seg ? Keff : Qeff;
        float v0 = (acc[n][m][0]+bb[0])*sc, v1 = (acc[n][m][1]+bb[1])*sc;
        float v2 = (acc[n][m][2]+bb[2])*sc, v3 = (acc[n][m][3]+bb[3])*sc;
        union { unsigned u[2]; unsigned long long ll; } W;
        W.u[0] = pk2bf(v0,v1); W.u[1] = pk2bf(v2,v3);
        *(unsigned long long*)&E[(((size_t)b_*NHh+hh)*Sq+ss)*HDq + d] = W.ll;
      }
    }
  } else {
    const int row0 = (xb-16)*128, col0 = yb*128;
    gemm_core_gl(wT + (size_t)2*HIDq*HIDq + (size_t)row0*HIDq, xbf + (size_t)col0*HIDq,
                 As, Bs, t, wv, lane, wr, wc, lr, g, acc);
    #pragma unroll
    for (int n=0;n<4;n++){
      #pragma unroll
      for (int m=0;m<4;m++){
        int chan = row0 + wr + m*16 + lr;
        int hh = chan>>6, d = chan&63;
        float bv = v_b[chan];
        int colb = col0 + wc + n*16 + g*4;
        int b_ = colb>>11, ss = colb&2047;
        i32x4 mk = *(const i32x4*)&mask[(size_t)b_*Sq + ss];   // zero masked V rows
        float m0 = mk[0]?1.f:0.f, m1 = mk[1]?1.f:0.f, m2 = mk[2]?1.f:0.f, m3 = mk[3]?1.f:0.f;
        union { unsigned u[2]; unsigned long long ll; } W;
        W.u[0] = pk2bf((acc[n][m][0]+bv)*m0, (acc[n][m][1]+bv)*m1);
        W.u[1] = pk2bf((acc[n][m][2]+bv)*m2, (acc[n][m][3]+bv)*m3);
        *(unsigned long long*)&Vt[(((size_t)b_*NHh+hh)*HDq + d)*Sq + ss] = W.ll;
      }
    }
  }
}

// ------------- output projection: 128x64 tile, grid 512 (2 blocks/CU) -------------
__global__ __launch_bounds__(256) void gemm_out(const unsigned short* __restrict__ A,
                                                const unsigned short* __restrict__ Bt,
                                                const float* __restrict__ bias,
                                                float* __restrict__ C){
  __shared__ unsigned short As[128*64];   // 16 KB
  __shared__ unsigned short Bs[64*64];    // 8 KB
  const int t = threadIdx.x;
  const int wv = t>>6, lane = t&63, g = lane>>4, lr = lane&15;
  const int wr = (wv>>1)*64, wc = (wv&1)*32;
  const int row0 = blockIdx.y*128, col0 = blockIdx.x*64;
  f32x4 acc[2][4] = {};
  for (int k0=0; k0<HIDq; k0+=64){
    __syncthreads();
    #pragma unroll
    for (int j=0;j<4;j++){
      int flat = t + j*256;
      int row = flat>>3, c = flat&7;
      int srcc = (c ^ (row&7))*8;
      gload_lds16(A + (size_t)(row0+row)*HIDq + k0 + srcc, &As[flat*8]);
    }
    #pragma unroll
    for (int j=0;j<2;j++){
      int flat = t + j*256;
      int row = flat>>3, c = flat&7;
      int srcc = (c ^ (row&7))*8;
      gload_lds16(Bt + (size_t)(col0+row)*HIDq + k0 + srcc, &Bs[flat*8]);
    }
    __syncthreads();
    #pragma unroll
    for (int ks=0; ks<2; ks++){
      bf16x8 af[4], bfv[2];
      #pragma unroll
      for (int m=0;m<4;m++){
        int rr = wr + m*16 + lr;
        af[m]  = *(bf16x8*)&As[rr*64 + (((ks*4+g) ^ (rr&7))*8)];
      }
      #pragma unroll
      for (int n=0;n<2;n++){
        int rr = wc + n*16 + lr;
        bfv[n] = *(bf16x8*)&Bs[rr*64 + (((ks*4+g) ^ (rr&7))*8)];
      }
      #pragma unroll
      for (int n=0;n<2;n++)
        #pragma unroll
        for (int m=0;m<4;m++)
          acc[n][m] = __builtin_amdgcn_mfma_f32_16x16x32_bf16(bfv[n], af[m], acc[n][m], 0,0,0);
    }
  }
  #pragma unroll
  for (int n=0;n<2;n++){
    #pragma unroll
    for (int m=0;m<4;m++){
      int row = row0 + wr + m*16 + lr;
      int colb = col0 + wc + n*16 + g*4;
      f32x4 bb = *(const f32x4*)&bias[colb];
      f32x4 o = acc[n][m] + bb;
      *(f32x4*)&C[(size_t)row*HIDq + colb] = o;
    }
  }
}

// ------------- flash attention: counted-vmcnt pipeline (T4), 3 K-bufs + 2 V-bufs -------------
// 40 KB LDS -> 4 blocks/CU at grid 1024. Per phase: issue K(i+2),V(i+1) stages;
// s_waitcnt vmcnt(8) (FIFO => K(i),V(i) landed); raw s_barrier; compute; raw s_barrier.
// P stays in registers (16x16x16 PV); mask folded into V rows + lsum mask-MFMA.
__global__ __launch_bounds__(256,4) void attn_kernel(
    const unsigned short* __restrict__ Qe, const unsigned short* __restrict__ Ke,
    const unsigned short* __restrict__ Vt, const float* __restrict__ Tb,
    const float* __restrict__ tbias, const unsigned short* __restrict__ Mbf,
    unsigned short* __restrict__ Obuf)
{
  __shared__ __align__(16) unsigned char smem[40960];
  unsigned short* Kb0 = (unsigned short*)smem;             // 8 KB each
  unsigned short* Kb1 = (unsigned short*)(smem + 8192);
  unsigned short* Kb2 = (unsigned short*)(smem + 16384);
  unsigned short* Vb0 = (unsigned short*)(smem + 24576);
  unsigned short* Vb1 = (unsigned short*)(smem + 32768);
  float* qls = (float*)smem;                               // overlay in Kb0..Kb2 (16.5 KB)
  unsigned short* qtls = Vb1;                              // overlay in Vb1 (5 KB)

  const int t = threadIdx.x;
  const int dd = blockIdx.x;
  const int slot = dd>>3, xcd = dd&7;
  const int x = slot & 31;
  const int bh = ((slot>>5)<<3) | xcd;
  const int h = bh & 15, b = bh >> 4;
  const int q0 = x*64;
  const int wv = t>>6, lane = t&63, g = lane>>4, lr = lane&15;

  const unsigned short* Qb  = Qe + (((size_t)b*NHh+h)*Sq + q0)*HDq;
  const unsigned short* Kb  = Ke + ((size_t)b*NHh+h)*(size_t)Sq*HDq;
  const unsigned short* Vtb = Vt + ((size_t)b*NHh+h)*(size_t)HDq*Sq;
  const unsigned short* Mbfb = Mbf + (size_t)b*Sq;

  // ---- prologue: qt = q_type(-log2e-scaled) @ T[h] ----
  {
    int row = t>>2, c8 = (t&3)*8;
    bf16x8 v = *(const bf16x8*)(Qb + (size_t)row*HDq + 32 + c8);
    #pragma unroll
    for (int j=0;j<8;j++) qls[row*33 + c8 + j] = bf2f((unsigned short)v[j]);
  }
  __syncthreads();
  {
    int row = t&63, e0 = (t>>6)*8;
    const float* Th = Tb + (size_t)h*1024;
    float a[8] = {};
    #pragma unroll 4
    for (int d=0; d<32; d++){
      float qd = qls[row*33 + d];
      const f32x4* tp = (const f32x4*)(Th + d*32 + e0);
      f32x4 t0 = tp[0], t1 = tp[1];
      a[0]+=qd*t0[0]; a[1]+=qd*t0[1]; a[2]+=qd*t0[2]; a[3]+=qd*t0[3];
      a[4]+=qd*t1[0]; a[5]+=qd*t1[1]; a[6]+=qd*t1[2]; a[7]+=qd*t1[3];
    }
    __syncthreads();   // qls reads done before qtls (Vb1) written
    union { unsigned u[2]; unsigned long long ll; } W0, W1;
    W0.u[0]=pk2bf(a[0],a[1]); W0.u[1]=pk2bf(a[2],a[3]);
    W1.u[0]=pk2bf(a[4],a[5]); W1.u[1]=pk2bf(a[6],a[7]);
    *(unsigned long long*)&qtls[row*40 + e0]     = W0.ll;
    *(unsigned long long*)&qtls[row*40 + e0 + 4] = W1.ll;
  }
  bf16x8 qvf = *(const bf16x8*)(Qb + (size_t)(wv*16+lr)*HDq + g*8);   // val half (prescaled)
  __syncthreads();
  bf16x8 qtn = *(const bf16x8*)&qtls[(wv*16+lr)*40 + g*8];            // type half (neg-scaled)
  __syncthreads();   // qtn reads done before Vb1 reused by staging

  // ---- prologue staging: K(0)->Kb0, V(0)->Vb0, K(1)->Kb1; drain once ----
  #pragma unroll
  for (int i=0;i<2;i++){
    int c = t + i*256;
    int kr = c>>3, kc = c&7;
    gload_lds16(Kb + (size_t)kr*HDq + ((kc ^ (kr&7))*8), Kb0 + c*8);
    int vd = c>>3, vc = c&7;
    gload_lds16(Vtb + (size_t)vd*Sq + ((vc ^ (vd&7))*8), Vb0 + c*8);
    gload_lds16(Kb + (size_t)(64+kr)*HDq + ((kc ^ (kr&7))*8), Kb1 + c*8);
  }
  __syncthreads();   // one full drain at block start only

  const float tbn = -tbias[h]*LOG2E;
  const f32x4 tbc = {tbn,tbn,tbn,tbn};
  const f32x4 zf = {0.f,0.f,0.f,0.f};
  f32x4 oT[4] = {};                 // oT[db][r] = O[q=4g+r][d=db*16+lr]
  f32x4 lsum = {0.f,0.f,0.f,0.f};   // lsum[r] for q=4g+r

  // one 64-key phase with counted-vmcnt pipeline
  auto phase = [&](const unsigned short* Kc, const unsigned short* Vc, int key0,
                   bool stK, int keyK, unsigned short* Kn,
                   bool stV, int keyV, unsigned short* Vn, bool vm8){
    if (stK){
      #pragma unroll
      for (int i=0;i<2;i++){
        int c = t + i*256;
        int kr = c>>3, kc = c&7;
        gload_lds16(Kb + (size_t)(keyK+kr)*HDq + ((kc ^ (kr&7))*8), Kn + c*8);
      }
    }
    if (stV){
      #pragma unroll
      for (int i=0;i<2;i++){
        int c = t + i*256;
        int vd = c>>3, vc = c&7;
        gload_lds16(Vtb + (size_t)vd*Sq + keyV + ((vc ^ (vd&7))*8), Vn + c*8);
      }
    }
    if (vm8) asm volatile("s_waitcnt vmcnt(8)" ::: "memory");
    else     asm volatile("s_waitcnt vmcnt(4)" ::: "memory");
    __builtin_amdgcn_sched_barrier(0);
    __builtin_amdgcn_s_barrier();        // all waves' tile-i stages landed

    // QK^T swapped: lane holds P[q=lr][k = 16ks+4g+r]
    f32x4 sv[4], st[4];
    __builtin_amdgcn_s_setprio(1);
    #pragma unroll
    for (int ks=0; ks<4; ks++){
      const unsigned short* kb = Kc + (ks*16+lr)*64;
      bf16x8 kf0 = *(const bf16x8*)(kb + (((g  ) ^ (lr&7))*8));
      bf16x8 kf1 = *(const bf16x8*)(kb + (((4+g) ^ (lr&7))*8));
      sv[ks] = __builtin_amdgcn_mfma_f32_16x16x32_bf16(kf0, qvf, zf, 0,0,0);
      st[ks] = __builtin_amdgcn_mfma_f32_16x16x32_bf16(kf1, qtn, tbc, 0,0,0);
    }
    __builtin_amdgcn_s_setprio(0);
    // p = exp2(sv) * sigmoid2(st); pack into x16 A-fragments (q=lr, k_local=4g+j)
    bf16x4 pa[4];
    #pragma unroll
    for (int ks=0; ks<4; ks++){
      float p0 = EXP2F(sv[ks][0]) * RCPF(1.f + EXP2F(st[ks][0]));
      float p1 = EXP2F(sv[ks][1]) * RCPF(1.f + EXP2F(st[ks][1]));
      float p2 = EXP2F(sv[ks][2]) * RCPF(1.f + EXP2F(st[ks][2]));
      float p3 = EXP2F(sv[ks][3]) * RCPF(1.f + EXP2F(st[ks][3]));
      union { unsigned u[2]; bf16x4 v; } P_;
      P_.u[0] = pk2bf(p0,p1); P_.u[1] = pk2bf(p2,p3);
      pa[ks] = P_.v;
    }
    // PV: O[q][d] += P[q][k] V[k][d] via 16x16x16; lsum via mask B-fragment
    #pragma unroll
    for (int ks=0; ks<4; ks++){
      bf16x4 mfr = *(const bf16x4*)(Mbfb + key0 + ks*16 + g*4);
      __builtin_amdgcn_s_setprio(1);
      lsum = MFMA16(pa[ks], mfr, lsum);
      #pragma unroll
      for (int db=0; db<4; db++){
        bf16x4 vf = *(const bf16x4*)(Vc + (db*16+lr)*64 + (((2*ks + (g>>1)) ^ (lr&7))*8 + 4*(g&1)));
        oT[db] = MFMA16(pa[ks], vf, oT[db]);
      }
      __builtin_amdgcn_s_setprio(0);
    }
    __builtin_amdgcn_s_barrier();        // readers done before bufs reused
  };

  // 30 phases in 5 groups of 6 (K buffers period 3, V buffers period 2), then 2 tail phases
  for (int j=0; j<5; j++){
    int kt = j*384;
    phase(Kb0, Vb0, kt,      true, kt+128, Kb2,  true, kt+64,  Vb1, true);
    phase(Kb1, Vb1, kt+64,   true, kt+192, Kb0,  true, kt+128, Vb0, true);
    phase(Kb2, Vb0, kt+128,  true, kt+256, Kb1,  true, kt+192, Vb1, true);
    phase(Kb0, Vb1, kt+192,  true, kt+320, Kb2,  true, kt+256, Vb0, true);
    phase(Kb1, Vb0, kt+256,  true, kt+384, Kb0,  true, kt+320, Vb1, true);
    phase(Kb2, Vb1, kt+320,  (kt+448 < Sq), kt+448, Kb1,  true, kt+384, Vb0, true);
  }
  phase(Kb0, Vb0, 1920,  false, 0, Kb0,  true, 1984, Vb1, false);   // i=30
  phase(Kb1, Vb1, 1984,  false, 0, Kb0,  false, 0, Vb0,  false);    // i=31

  // ---- epilogue: lane (g,lr) holds O[q = wv*16+4g+r][d = db*16+lr] ----
  float linv[4];
  #pragma unroll
  for (int r=0;r<4;r++) linv[r] = (lsum[r] > 0.f) ? RCPF(lsum[r]) : 0.f;
  unsigned short* Ob = Obuf + ((size_t)b*Sq + (q0 + wv*16 + g*4))*HIDq + h*HDq + lr;
  #pragma unroll
  for (int db=0; db<4; db++){
    #pragma unroll
    for (int r=0;r<4;r++)
      Ob[(size_t)r*HIDq + db*16] = f2bf(oT[db][r]*linv[r]);
  }
}

extern "C" void kernel_launch(void* const* d_in, const int* in_sizes, int n_in,
                              void* d_out, int out_size, void* d_ws, size_t ws_size,
                              hipStream_t stream) {
  const float* x     = (const float*)d_in[0];
  const float* q_w   = (const float*)d_in[1];
  const float* q_b   = (const float*)d_in[2];
  const float* k_w   = (const float*)d_in[3];
  const float* k_b   = (const float*)d_in[4];
  const float* v_w   = (const float*)d_in[5];
  const float* v_b   = (const float*)d_in[6];
  const float* out_w = (const float*)d_in[7];
  const float* out_b = (const float*)d_in[8];
  const float* Tb    = (const float*)d_in[9];
  const float* tbias = (const float*)d_in[10];
  const int*   mask  = (const int*)d_in[11];

  const size_t MROWS = 4096;             // B*S
  unsigned short* xbf  = (unsigned short*)d_ws;           // 4M shorts
  unsigned short* wT   = xbf  + MROWS*HIDq;               // 4 x 1M
  unsigned short* Qeff = wT   + (size_t)4*HIDq*HIDq;      // (B,NH,S,HD), prescaled
  unsigned short* Keff = Qeff + MROWS*HIDq;
  unsigned short* Vt   = Keff + MROWS*HIDq;               // (B,NH,HD,S) transposed, masked rows zeroed
  unsigned short* Obuf = Vt   + MROWS*HIDq;               // (B,S,HID) bf16
  unsigned short* Mbf  = Obuf + MROWS*HIDq;               // (B,S) bf16 0/1 mask

  int n8 = (int)(MROWS*HIDq/8);
  convert_x<<<dim3(n8/256 + 2), dim3(256), 0, stream>>>(x, xbf, n8, mask, Mbf);
  transpose_w<<<dim3(32,32,4), dim3(32,8), 0, stream>>>(q_w, k_w, v_w, out_w, wT);

  gemm_qkv<<<dim3(24,32), dim3(256), 0, stream>>>(xbf, wT, q_b, k_b, v_b, mask, Qeff, Keff, Vt);

  attn_kernel<<<dim3(1024), dim3(256), 0, stream>>>(Qeff, Keff, Vt, Tb, tbias, Mbf, Obuf);

  gemm_out<<<dim3(16,32), dim3(256), 0, stream>>>(Obuf, wT + (size_t)3*HIDq*HIDq, out_b, (float*)d_out);
}